// Round 8
// baseline (731.347 us; speedup 1.0000x reference)
//
#include <hip/hip_runtime.h>
#include <hip/hip_bf16.h>
#include <math.h>

// Problem constants (PoseMixtureVAE)
#define N_BATCH 4096
#define FRAME   267
#define LATENT  32
#define HIDDEN  256
#define GATE_H  64
#define EXPERTS 6
#define NBLK    512     // persistent grid; co-resident (LDS 45.5KB->3/CU, lb(256,2)->2/CU)

typedef __hip_bfloat16 bf16;
typedef __bf16  bf16x8 __attribute__((ext_vector_type(8)));
typedef float   f32x4  __attribute__((ext_vector_type(4)));

__device__ __forceinline__ float eluf(float v) { return (v > 0.f) ? v : (expf(v) - 1.f); }

// ---------------------------------------------------------------------------
// Device-scope sense-reversing grid barrier. All NBLK blocks co-resident.
// __threadfence() on gfx950 = agent-scope fence (L1 inv + L2 wb/inv) -> makes
// pre-barrier stores visible cross-XCD (G16).
// ---------------------------------------------------------------------------
__device__ __forceinline__ void grid_barrier(unsigned* cnt, unsigned* gen) {
    __syncthreads();
    if (threadIdx.x == 0) {
        __threadfence();
        unsigned g = __hip_atomic_load(gen, __ATOMIC_RELAXED, __HIP_MEMORY_SCOPE_AGENT);
        unsigned a = __hip_atomic_fetch_add(cnt, 1u, __ATOMIC_ACQ_REL, __HIP_MEMORY_SCOPE_AGENT);
        if (a == NBLK - 1) {
            __hip_atomic_store(cnt, 0u, __ATOMIC_RELAXED, __HIP_MEMORY_SCOPE_AGENT);
            __hip_atomic_store(gen, g + 1u, __ATOMIC_RELEASE, __HIP_MEMORY_SCOPE_AGENT);
        } else {
            while (__hip_atomic_load(gen, __ATOMIC_ACQUIRE, __HIP_MEMORY_SCOPE_AGENT) == g)
                __builtin_amdgcn_s_sleep(1);
        }
        __threadfence();
    }
    __syncthreads();
}

struct WEnt { const float* src; bf16* dst; int K, M, Mtot, mOff, Ksteps, Mtiles, cum; };
struct WTab { WEnt e[10]; int total; };

struct Args {
    const float *x, *c, *eps;
    const float *enc_b1, *enc_b2, *g_b0, *g_b1, *g_b2, *b0, *b1, *b2;
    const float *enc_bmu, *enc_blv;
    float *out_layer, *out_mu, *out_lv;
    unsigned *bar;                       // [0]=cnt, [1]=gen (memset 0 on stream)
    float *co, *biasCat;
    bf16 *Axc, *Axh1, *Axh2, *Azc, *Azd1, *Azd2;
    bf16 *Wt_e1, *Wt_e2, *Wt_ml, *Wt_g0, *Wt_g1, *Wt_g2, *Wt_w0, *Wt_w1, *Wt_w2;
};

// LDS: region0 = sA (max 32x552 bf16 = 35328B), region1 = 11264B scratch
#define R0_BYTES 35328
#define R1_BYTES 11264

// ---------------------------------------------------------------------------
// GEMM stage: C[n,m] = act( sum_e coeff[n,e]*(A[n,:] @ We + bias_e) )
// 32 rows x tilesPB*16 cols per block; A full-K in LDS; B streamed to regs.
// ---------------------------------------------------------------------------
template<int KSTEPS, int E>
__device__ void gemm_stage(const bf16* __restrict__ A, const bf16* __restrict__ Wt,
                           const float* __restrict__ bias, const float* __restrict__ coeff,
                           int M, int Mtot, int tilesPB,
                           float* __restrict__ Cf, int ldc,
                           bf16* __restrict__ Cb, int ldcb, int act,
                           int rb, int cb, bf16* sA, float* sCo, int tid)
{
    constexpr int Kpad = KSTEPS * 32;
    constexpr int strideA = Kpad + 8;
    const int w = tid >> 6, lane = tid & 63, ml = lane & 15, quad = lane >> 4;
    const int row0 = rb * 32, colbase = cb * tilesPB * 16;

    for (int idx = tid; idx < 32 * E; idx += 256) {
        const int e = idx >> 5, r = idx & 31;
        sCo[idx] = coeff ? coeff[(size_t)(row0 + r) * EXPERTS + e] : 1.f;
    }
    {
        const int r = tid >> 3, kt = (tid & 7) * 8;
        for (int kk = kt; kk < Kpad; kk += 64)
            *(float4*)(sA + r * strideA + kk) =
                *(const float4*)(A + (size_t)(row0 + r) * Kpad + kk);
    }
    __syncthreads();

    for (int ct = w; ct < tilesPB; ct += 4) {
        const int col = colbase + ct * 16 + ml;
        f32x4 acc0 = (f32x4){0.f, 0.f, 0.f, 0.f};
        f32x4 acc1 = (f32x4){0.f, 0.f, 0.f, 0.f};
        for (int e = 0; e < E; ++e) {
            f32x4 p0 = (f32x4){0.f, 0.f, 0.f, 0.f};
            f32x4 p1 = (f32x4){0.f, 0.f, 0.f, 0.f};
            const bf16* wp = Wt + ((size_t)e * KSTEPS * Mtot + col) * 32 + quad * 8;
            #pragma unroll
            for (int ks = 0; ks < KSTEPS; ++ks) {
                const bf16x8 b  = *(const bf16x8*)(wp + (size_t)ks * Mtot * 32);
                const bf16x8 a0 = *(const bf16x8*)(sA + ml * strideA + ks * 32 + quad * 8);
                const bf16x8 a1 = *(const bf16x8*)(sA + (16 + ml) * strideA + ks * 32 + quad * 8);
                p0 = __builtin_amdgcn_mfma_f32_16x16x32_bf16(a0, b, p0, 0, 0, 0);
                p1 = __builtin_amdgcn_mfma_f32_16x16x32_bf16(a1, b, p1, 0, 0, 0);
            }
            const float bv = (col < M) ? bias[(size_t)e * M + col] : 0.f;
            #pragma unroll
            for (int rg = 0; rg < 4; ++rg) {
                acc0[rg] += sCo[e * 32 + quad * 4 + rg]      * (p0[rg] + bv);
                acc1[rg] += sCo[e * 32 + 16 + quad * 4 + rg] * (p1[rg] + bv);
            }
        }
        if (col < M) {
            #pragma unroll
            for (int rg = 0; rg < 4; ++rg) {
                const int r0g = row0 + quad * 4 + rg, r1g = r0g + 16;
                float v0 = acc0[rg], v1 = acc1[rg];
                if (act) { v0 = eluf(v0); v1 = eluf(v1); }
                if (Cf) { Cf[(size_t)r0g * ldc + col] = v0; Cf[(size_t)r1g * ldc + col] = v1; }
                if (Cb) { Cb[(size_t)r0g * ldcb + col] = __float2bfloat16(v0);
                          Cb[(size_t)r1g * ldcb + col] = __float2bfloat16(v1); }
            }
        }
    }
}

// ---------------------------------------------------------------------------
__global__ __launch_bounds__(256, 2) void fused(Args a, WTab tab) {
    __shared__ char smem[R0_BYTES + R1_BYTES];
    bf16* sA  = (bf16*)smem;
    char* r1  = smem + R0_BYTES;
    const int tid = threadIdx.x;
    const int bid = blockIdx.x;
    const int w = tid >> 6, lane = tid & 63, ml = lane & 15, quad = lane >> 4;

    // ================= S0: input conversion + weight repack =================
    if (bid == 0 && tid < 64)
        a.biasCat[tid] = (tid < 32) ? a.enc_bmu[tid] : a.enc_blv[tid - 32];
    #pragma unroll 1
    for (int i = 0; i < 8; ++i) {
        const int r = bid * 8 + i;
        for (int col = tid; col < 544; col += 256) {
            const size_t o = (size_t)r * 544 + col;
            float vx = 0.f;
            if (col < FRAME)          vx = a.x[(size_t)r * FRAME + col];
            else if (col < 2 * FRAME) vx = a.c[(size_t)r * FRAME + col - FRAME];
            a.Axc[o] = __float2bfloat16(vx);
            if (col < FRAME) {
                const bf16 v = __float2bfloat16(a.x[(size_t)r * FRAME + col]);
                a.Axh1[o] = v; a.Axh2[o] = v;
            } else if (col >= FRAME + HIDDEN) {
                const bf16 zv = __float2bfloat16(0.f);
                a.Axh1[o] = zv; a.Axh2[o] = zv;
            }
            if (col >= 32 && col < 320) {
                const float vc = (col < 32 + FRAME) ? a.c[(size_t)r * FRAME + col - 32] : 0.f;
                a.Azc[(size_t)r * 320 + col] = __float2bfloat16(vc);
            }
        }
    }
    {   // weight repack units, strided over blocks
        float (*tbuf)[33] = (float(*)[33])r1;   // 32x33 f32 = 4224B
        const int tx = tid & 31, ty = tid >> 5;
        #pragma unroll 1
        for (int u = bid; u < tab.total; u += NBLK) {
            int i = 0;
            while (i < 9 && u >= tab.e[i + 1].cum) ++i;
            const WEnt en = tab.e[i];
            const int t = u - en.cum;
            const int perE = en.Ksteps * en.Mtiles;
            const int e = t / perE;
            const int rr = t - e * perE;
            const int mt = rr / en.Ksteps;
            const int ks = rr - mt * en.Ksteps;
            const float* src = en.src + (size_t)e * en.K * en.M;
            __syncthreads();
            #pragma unroll
            for (int i0 = 0; i0 < 32; i0 += 8) {
                const int k = ks * 32 + i0 + ty, m = mt * 32 + tx;
                tbuf[i0 + ty][tx] = (k < en.K && m < en.M) ? src[(size_t)k * en.M + m] : 0.f;
            }
            __syncthreads();
            bf16* dst = en.dst + ((size_t)(e * en.Ksteps + ks) * en.Mtot + en.mOff + mt * 32) * 32;
            #pragma unroll
            for (int i0 = 0; i0 < 32; i0 += 8)
                dst[(size_t)(i0 + ty) * 32 + tx] = __float2bfloat16(tbuf[tx][i0 + ty]);
        }
    }
    grid_barrier(a.bar, a.bar + 1);

    // ================= S1: h1 = elu([x|c]@W+b) -> Axh1[:,267:523] ===========
    gemm_stage<17, 1>(a.Axc, a.Wt_e1, a.enc_b1, nullptr, 256, 256, 4,
                      nullptr, 0, a.Axh1 + FRAME, 544, 1, bid >> 2, bid & 3, sA, (float*)r1, tid);
    grid_barrier(a.bar, a.bar + 1);

    // ================= S2: h2 = elu([x|h1]@W+b) -> Axh2[:,267:523] ==========
    gemm_stage<17, 1>(a.Axh1, a.Wt_e2, a.enc_b2, nullptr, 256, 256, 4,
                      nullptr, 0, a.Axh2 + FRAME, 544, 1, bid >> 2, bid & 3, sA, (float*)r1, tid);
    grid_barrier(a.bar, a.bar + 1);

    // ====== S3: mu|lv GEMM + z + full gate chain + softmax (128 blocks) =====
    if (bid < 128) {
        const int row0 = bid * 32;
        float* sML = (float*)r1;                       // 32x64 f32 = 8KB
        {   // stage Axh2 rows (Kpad 544, stride 552)
            const int r = tid >> 3, kt = (tid & 7) * 8;
            for (int kk = kt; kk < 544; kk += 64)
                *(float4*)(sA + r * 552 + kk) =
                    *(const float4*)(a.Axh2 + (size_t)(row0 + r) * 544 + kk);
        }
        __syncthreads();
        {   // mu|lv: M=64, each wave 16 cols
            const int col = 16 * w + ml;
            f32x4 p0 = (f32x4){0.f, 0.f, 0.f, 0.f};
            f32x4 p1 = (f32x4){0.f, 0.f, 0.f, 0.f};
            const bf16* wp = a.Wt_ml + (size_t)col * 32 + quad * 8;
            #pragma unroll
            for (int ks = 0; ks < 17; ++ks) {
                const bf16x8 b  = *(const bf16x8*)(wp + (size_t)ks * 64 * 32);
                const bf16x8 a0 = *(const bf16x8*)(sA + ml * 552 + ks * 32 + quad * 8);
                const bf16x8 a1 = *(const bf16x8*)(sA + (16 + ml) * 552 + ks * 32 + quad * 8);
                p0 = __builtin_amdgcn_mfma_f32_16x16x32_bf16(a0, b, p0, 0, 0, 0);
                p1 = __builtin_amdgcn_mfma_f32_16x16x32_bf16(a1, b, p1, 0, 0, 0);
            }
            const float bv = a.biasCat[col];
            #pragma unroll
            for (int rg = 0; rg < 4; ++rg) {
                sML[(quad * 4 + rg) * 64 + col]      = p0[rg] + bv;
                sML[(16 + quad * 4 + rg) * 64 + col] = p1[rg] + bv;
            }
        }
        __syncthreads();
        for (int i = tid; i < 32 * LATENT; i += 256) {
            const int r = i >> 5, l = i & 31;
            const float m  = sML[r * 64 + l];
            const float lv = sML[r * 64 + 32 + l];
            const int gi = (row0 + r) * LATENT + l;
            a.out_mu[gi] = m; a.out_lv[gi] = lv;
            const bf16 zb = __float2bfloat16(m + a.eps[gi] * expf(0.5f * lv));
            a.Azc [(size_t)(row0 + r) * 320 + l] = zb;
            a.Azd1[(size_t)(row0 + r) * 288 + l] = zb;
            a.Azd2[(size_t)(row0 + r) * 288 + l] = zb;
        }
        __syncthreads();
        {   // gate A = Azc rows [z|c] (Kpad 320, stride 328)
            const int r = tid >> 3, kt = (tid & 7) * 8;
            for (int kk = kt; kk < 320; kk += 64)
                *(float4*)(sA + r * 328 + kk) =
                    *(const float4*)(a.Azc + (size_t)(row0 + r) * 320 + kk);
        }
        bf16*  sG1 = (bf16*)r1;                        // 32x72 bf16
        bf16*  sG2 = (bf16*)(r1 + 4608);
        float* sLg = (float*)(r1 + 9216);              // 32x16 f32
        __syncthreads();
        {   // g1: K=320(10), M=64
            const int col = 16 * w + ml;
            f32x4 p0 = (f32x4){0.f, 0.f, 0.f, 0.f};
            f32x4 p1 = (f32x4){0.f, 0.f, 0.f, 0.f};
            const bf16* wp = a.Wt_g0 + (size_t)col * 32 + quad * 8;
            #pragma unroll
            for (int ks = 0; ks < 10; ++ks) {
                const bf16x8 b  = *(const bf16x8*)(wp + (size_t)ks * 64 * 32);
                const bf16x8 a0 = *(const bf16x8*)(sA + ml * 328 + ks * 32 + quad * 8);
                const bf16x8 a1 = *(const bf16x8*)(sA + (16 + ml) * 328 + ks * 32 + quad * 8);
                p0 = __builtin_amdgcn_mfma_f32_16x16x32_bf16(a0, b, p0, 0, 0, 0);
                p1 = __builtin_amdgcn_mfma_f32_16x16x32_bf16(a1, b, p1, 0, 0, 0);
            }
            const float bv = a.g_b0[col];
            #pragma unroll
            for (int rg = 0; rg < 4; ++rg) {
                sG1[(quad * 4 + rg) * 72 + col]      = __float2bfloat16(eluf(p0[rg] + bv));
                sG1[(16 + quad * 4 + rg) * 72 + col] = __float2bfloat16(eluf(p1[rg] + bv));
            }
        }
        __syncthreads();
        {   // g2: K=64(2), M=64
            const int col = 16 * w + ml;
            f32x4 p0 = (f32x4){0.f, 0.f, 0.f, 0.f};
            f32x4 p1 = (f32x4){0.f, 0.f, 0.f, 0.f};
            const bf16* wp = a.Wt_g1 + (size_t)col * 32 + quad * 8;
            #pragma unroll
            for (int ks = 0; ks < 2; ++ks) {
                const bf16x8 b  = *(const bf16x8*)(wp + (size_t)ks * 64 * 32);
                const bf16x8 a0 = *(const bf16x8*)(sG1 + ml * 72 + ks * 32 + quad * 8);
                const bf16x8 a1 = *(const bf16x8*)(sG1 + (16 + ml) * 72 + ks * 32 + quad * 8);
                p0 = __builtin_amdgcn_mfma_f32_16x16x32_bf16(a0, b, p0, 0, 0, 0);
                p1 = __builtin_amdgcn_mfma_f32_16x16x32_bf16(a1, b, p1, 0, 0, 0);
            }
            const float bv = a.g_b1[col];
            #pragma unroll
            for (int rg = 0; rg < 4; ++rg) {
                sG2[(quad * 4 + rg) * 72 + col]      = __float2bfloat16(eluf(p0[rg] + bv));
                sG2[(16 + quad * 4 + rg) * 72 + col] = __float2bfloat16(eluf(p1[rg] + bv));
            }
        }
        __syncthreads();
        if (w == 0) {   // logits: K=64(2), M=6 (Mtot 32)
            f32x4 p0 = (f32x4){0.f, 0.f, 0.f, 0.f};
            f32x4 p1 = (f32x4){0.f, 0.f, 0.f, 0.f};
            const bf16* wp = a.Wt_g2 + (size_t)ml * 32 + quad * 8;
            #pragma unroll
            for (int ks = 0; ks < 2; ++ks) {
                const bf16x8 b  = *(const bf16x8*)(wp + (size_t)ks * 32 * 32);
                const bf16x8 a0 = *(const bf16x8*)(sG2 + ml * 72 + ks * 32 + quad * 8);
                const bf16x8 a1 = *(const bf16x8*)(sG2 + (16 + ml) * 72 + ks * 32 + quad * 8);
                p0 = __builtin_amdgcn_mfma_f32_16x16x32_bf16(a0, b, p0, 0, 0, 0);
                p1 = __builtin_amdgcn_mfma_f32_16x16x32_bf16(a1, b, p1, 0, 0, 0);
            }
            const float bv = (ml < EXPERTS) ? a.g_b2[ml] : 0.f;
            #pragma unroll
            for (int rg = 0; rg < 4; ++rg) {
                sLg[(quad * 4 + rg) * 16 + ml]      = p0[rg] + bv;
                sLg[(16 + quad * 4 + rg) * 16 + ml] = p1[rg] + bv;
            }
        }
        __syncthreads();
        if (tid < 32) {
            float v[EXPERTS];
            float m = -1e30f;
            #pragma unroll
            for (int i = 0; i < EXPERTS; ++i) { v[i] = sLg[tid * 16 + i]; m = fmaxf(m, v[i]); }
            float s = 0.f;
            #pragma unroll
            for (int i = 0; i < EXPERTS; ++i) { v[i] = expf(v[i] - m); s += v[i]; }
            const float inv = 1.f / s;
            #pragma unroll
            for (int i = 0; i < EXPERTS; ++i)
                a.co[(size_t)(row0 + tid) * EXPERTS + i] = v[i] * inv;
        }
    }
    grid_barrier(a.bar, a.bar + 1);

    // ================= S4: dh1 -> Azd1[:,32:288] ============================
    gemm_stage<10, EXPERTS>(a.Azc, a.Wt_w0, a.b0, a.co, 256, 256, 4,
                            nullptr, 0, a.Azd1 + LATENT, 288, 1, bid >> 2, bid & 3, sA, (float*)r1, tid);
    grid_barrier(a.bar, a.bar + 1);

    // ================= S5: dh2 -> Azd2[:,32:288] ============================
    gemm_stage<9, EXPERTS>(a.Azd1, a.Wt_w1, a.b1, a.co, 256, 256, 4,
                           nullptr, 0, a.Azd2 + LATENT, 288, 1, bid >> 2, bid & 3, sA, (float*)r1, tid);
    grid_barrier(a.bar, a.bar + 1);

    // ================= S6: out -> d_out (f32) ===============================
    gemm_stage<9, EXPERTS>(a.Azd2, a.Wt_w2, a.b2, a.co, FRAME, 320, 5,
                           a.out_layer, FRAME, nullptr, 0, 0, bid >> 2, bid & 3, sA, (float*)r1, tid);
}

// ---------------------------------------------------------------------------
extern "C" void kernel_launch(void* const* d_in, const int* in_sizes, int n_in,
                              void* d_out, int out_size, void* d_ws, size_t ws_size,
                              hipStream_t stream) {
    Args a;
    a.x       = (const float*)d_in[0];
    a.c       = (const float*)d_in[1];
    a.eps     = (const float*)d_in[2];
    const float* enc_w1  = (const float*)d_in[3];
    a.enc_b1  = (const float*)d_in[4];
    const float* enc_w2  = (const float*)d_in[5];
    a.enc_b2  = (const float*)d_in[6];
    const float* enc_wmu = (const float*)d_in[7];
    a.enc_bmu = (const float*)d_in[8];
    const float* enc_wlv = (const float*)d_in[9];
    a.enc_blv = (const float*)d_in[10];
    const float* g_w0    = (const float*)d_in[11];
    a.g_b0    = (const float*)d_in[12];
    const float* g_w1    = (const float*)d_in[13];
    a.g_b1    = (const float*)d_in[14];
    const float* g_w2    = (const float*)d_in[15];
    a.g_b2    = (const float*)d_in[16];
    const float* w0      = (const float*)d_in[17];
    a.b0      = (const float*)d_in[18];
    const float* w1      = (const float*)d_in[19];
    a.b1      = (const float*)d_in[20];
    const float* w2      = (const float*)d_in[21];
    a.b2      = (const float*)d_in[22];

    a.out_layer = (float*)d_out;
    a.out_mu    = a.out_layer + (size_t)N_BATCH * FRAME;
    a.out_lv    = a.out_mu    + (size_t)N_BATCH * LATENT;

    // ---- workspace layout (16B-aligned) ----
    char* p = (char*)d_ws;
    a.bar     = (unsigned*)p;  p += 64;
    a.co      = (float*)p;     p += (size_t)N_BATCH * EXPERTS * 4;
    a.biasCat = (float*)p;     p += 64 * 4;
    a.Axc  = (bf16*)p;         p += (size_t)N_BATCH * 544 * 2;
    a.Axh1 = (bf16*)p;         p += (size_t)N_BATCH * 544 * 2;
    a.Axh2 = (bf16*)p;         p += (size_t)N_BATCH * 544 * 2;
    a.Azc  = (bf16*)p;         p += (size_t)N_BATCH * 320 * 2;
    a.Azd1 = (bf16*)p;         p += (size_t)N_BATCH * 288 * 2;
    a.Azd2 = (bf16*)p;         p += (size_t)N_BATCH * 288 * 2;
    a.Wt_e1 = (bf16*)p;        p += (size_t)17 * 256 * 32 * 2;
    a.Wt_e2 = (bf16*)p;        p += (size_t)17 * 256 * 32 * 2;
    a.Wt_ml = (bf16*)p;        p += (size_t)17 * 64 * 32 * 2;
    a.Wt_g0 = (bf16*)p;        p += (size_t)10 * 64 * 32 * 2;
    a.Wt_g1 = (bf16*)p;        p += (size_t)2 * 64 * 32 * 2;
    a.Wt_g2 = (bf16*)p;        p += (size_t)2 * 32 * 32 * 2;
    a.Wt_w0 = (bf16*)p;        p += (size_t)EXPERTS * 10 * 256 * 32 * 2;
    a.Wt_w1 = (bf16*)p;        p += (size_t)EXPERTS * 9 * 256 * 32 * 2;
    a.Wt_w2 = (bf16*)p;        p += (size_t)EXPERTS * 9 * 320 * 32 * 2;

    WTab tab;
    int cum = 0, n = 0;
    auto add = [&](const float* src, bf16* dst, int K, int M, int Mtot, int mOff, int E) {
        int Ksteps;
        if (K == 534 || K == 523) Ksteps = 17;
        else if (K == 299) Ksteps = 10;
        else if (K == 288) Ksteps = 9;
        else Ksteps = 2;   // K=64
        const int Mtiles = (M + 31) / 32;
        tab.e[n] = {src, dst, K, M, Mtot, mOff, Ksteps, Mtiles, cum};
        cum += E * Ksteps * Mtiles;
        ++n;
    };
    add(enc_w1,  a.Wt_e1, 534, 256, 256, 0, 1);
    add(enc_w2,  a.Wt_e2, 523, 256, 256, 0, 1);
    add(enc_wmu, a.Wt_ml, 523, 32, 64, 0, 1);
    add(enc_wlv, a.Wt_ml, 523, 32, 64, 32, 1);
    add(g_w0,    a.Wt_g0, 299, 64, 64, 0, 1);
    add(g_w1,    a.Wt_g1, 64, 64, 64, 0, 1);
    add(g_w2,    a.Wt_g2, 64, 6, 32, 0, 1);
    add(w0,      a.Wt_w0, 299, 256, 256, 0, EXPERTS);
    add(w1,      a.Wt_w1, 288, 256, 256, 0, EXPERTS);
    add(w2,      a.Wt_w2, 288, 267, 320, 0, EXPERTS);
    tab.total = cum;

    hipMemsetAsync(a.bar, 0, 64, stream);   // zero barrier state (poisoned 0xAA)
    fused<<<dim3(NBLK), dim3(256), 0, stream>>>(a, tab);
}

// Round 9
// 248.444 us; speedup vs baseline: 2.9437x; 2.9437x over previous
//
#include <hip/hip_runtime.h>
#include <hip/hip_bf16.h>
#include <math.h>

// Problem constants (PoseMixtureVAE)
#define N_BATCH 4096
#define FRAME   267
#define LATENT  32
#define HIDDEN  256
#define GATE_H  64
#define EXPERTS 6
// Kpads: [x|c]=534->544 (17 ksteps), [x|h]=523->544 (17), [z|c]=299->320 (10),
//        [z|h]=288 (9), gate hidden 64 (2)

typedef __hip_bfloat16 bf16;
typedef __bf16  bf16x8 __attribute__((ext_vector_type(8)));
typedef float   f32x4  __attribute__((ext_vector_type(4)));

__device__ __forceinline__ float eluf(float v) { return (v > 0.f) ? v : (expf(v) - 1.f); }

struct WEnt { const float* src; bf16* dst; int K, M, Mtot, mOff, Ksteps, Mtiles, cum; };
struct WTab { WEnt e[10]; int total; };

// ---------------------------------------------------------------------------
// prep: input conversion (blocks 0..511, 8 rows each) + weight repack
// (blocks 512.., one 32x32 tile unit each) + biasCat.
// ---------------------------------------------------------------------------
__global__ __launch_bounds__(256) void prep_kernel(
    const float* __restrict__ x, const float* __restrict__ c,
    const float* __restrict__ bmu, const float* __restrict__ blv,
    bf16* __restrict__ Axc, bf16* __restrict__ Axh1,
    bf16* __restrict__ Axh2, bf16* __restrict__ Azc,
    float* __restrict__ biasCat, WTab tab)
{
    const int tid = threadIdx.x, bid = blockIdx.x;
    if (bid < 512) {
        if (bid == 0 && tid < 64)
            biasCat[tid] = (tid < 32) ? bmu[tid] : blv[tid - 32];
        #pragma unroll 1
        for (int i = 0; i < 8; ++i) {
            const int r = bid * 8 + i;
            for (int col = tid; col < 544; col += 256) {
                const size_t o = (size_t)r * 544 + col;
                float vx = 0.f;
                if (col < FRAME)          vx = x[(size_t)r * FRAME + col];
                else if (col < 2 * FRAME) vx = c[(size_t)r * FRAME + col - FRAME];
                Axc[o] = __float2bfloat16(vx);
                if (col < FRAME) {
                    const bf16 v = __float2bfloat16(x[(size_t)r * FRAME + col]);
                    Axh1[o] = v; Axh2[o] = v;
                } else if (col >= FRAME + HIDDEN) {
                    const bf16 zv = __float2bfloat16(0.f);
                    Axh1[o] = zv; Axh2[o] = zv;
                }
                if (col >= 32 && col < 320) {
                    const float vc = (col < 32 + FRAME) ? c[(size_t)r * FRAME + col - 32] : 0.f;
                    Azc[(size_t)r * 320 + col] = __float2bfloat16(vc);
                }
            }
        }
        return;
    }
    // weight repack unit
    __shared__ float tbuf[32][33];
    const int u = bid - 512;
    int i = 0;
    while (i < 9 && u >= tab.e[i + 1].cum) ++i;
    const WEnt en = tab.e[i];
    const int t = u - en.cum;
    const int perE = en.Ksteps * en.Mtiles;
    const int e = t / perE;
    const int rr = t - e * perE;
    const int mt = rr / en.Ksteps;
    const int ks = rr - mt * en.Ksteps;
    const int tx = tid & 31, ty = tid >> 5;
    const float* src = en.src + (size_t)e * en.K * en.M;
    #pragma unroll
    for (int i0 = 0; i0 < 32; i0 += 8) {
        const int k = ks * 32 + i0 + ty, m = mt * 32 + tx;
        tbuf[i0 + ty][tx] = (k < en.K && m < en.M) ? src[(size_t)k * en.M + m] : 0.f;
    }
    __syncthreads();
    bf16* dst = en.dst + ((size_t)(e * en.Ksteps + ks) * en.Mtot + en.mOff + mt * 32) * 32;
    #pragma unroll
    for (int i0 = 0; i0 < 32; i0 += 8)
        dst[(size_t)(i0 + ty) * 32 + tx] = __float2bfloat16(tbuf[tx][i0 + ty]);
}

// ---------------------------------------------------------------------------
// MFMA GEMM: C[n,m] = act( sum_e coeff[n,e]*(A[n,:] @ We + bias_e) )
// RF = row-fragments/wave (ROWS = RF*16), TF = simultaneous col tiles/wave.
// Per k-step: TF B-loads feed RF*TF MFMAs (ILP hides global-load latency).
// A full-K in LDS (one barrier); B streamed to registers (coalesced, k-block
// contiguous repack [E][KSTEPS][Mtot][32]).
// ---------------------------------------------------------------------------
template<int KSTEPS, int E, int RF, int TF>
__global__ __launch_bounds__(256) void gemm_k(
    const bf16* __restrict__ A, const bf16* __restrict__ Wt,
    const float* __restrict__ bias, const float* __restrict__ coeff,
    int M, int Mtot, int tilesPB,
    float* __restrict__ Cf, int ldc, bf16* __restrict__ Cb, int ldcb, int act)
{
    constexpr int Kpad = KSTEPS * 32;
    constexpr int strideA = Kpad + 8;
    constexpr int ROWS = RF * 16;
    extern __shared__ char smem[];
    bf16*  sA  = (bf16*)smem;
    float* sCo = (float*)(smem + (size_t)ROWS * strideA * 2);

    const int tid = threadIdx.x;
    const int w = tid >> 6, lane = tid & 63, ml = lane & 15, quad = lane >> 4;
    const int row0 = blockIdx.y * ROWS;
    const int colbase = blockIdx.x * tilesPB * 16;

    for (int idx = tid; idx < ROWS * E; idx += 256) {
        const int e = idx / ROWS, r = idx % ROWS;
        sCo[idx] = coeff ? coeff[(size_t)(row0 + r) * EXPERTS + e] : 1.f;
    }
    {   // stage A: ROWS rows x Kpad
        constexpr int TPR = 256 / ROWS;
        const int r = tid / TPR, kt = (tid % TPR) * 8;
        for (int kk = kt; kk < Kpad; kk += TPR * 8)
            *(float4*)(sA + r * strideA + kk) =
                *(const float4*)(A + (size_t)(row0 + r) * Kpad + kk);
    }
    __syncthreads();

    for (int ctb = 0; ctb < tilesPB; ctb += 4 * TF) {
        const int ct0 = ctb + w;
        const bool v0 = ct0 < tilesPB;
        const int col0 = colbase + (v0 ? ct0 : 0) * 16 + ml;
        int col1 = col0; bool v1 = false;
        if constexpr (TF == 2) {
            const int ct1 = ctb + w + 4;
            v1 = ct1 < tilesPB;
            col1 = colbase + (v1 ? ct1 : 0) * 16 + ml;
        }
        f32x4 acc0[RF], acc1[RF];
        #pragma unroll
        for (int rt = 0; rt < RF; ++rt) {
            acc0[rt] = (f32x4){0.f, 0.f, 0.f, 0.f};
            acc1[rt] = (f32x4){0.f, 0.f, 0.f, 0.f};
        }
        for (int e = 0; e < E; ++e) {
            f32x4 p0[RF], p1[RF];
            #pragma unroll
            for (int rt = 0; rt < RF; ++rt) {
                p0[rt] = (f32x4){0.f, 0.f, 0.f, 0.f};
                p1[rt] = (f32x4){0.f, 0.f, 0.f, 0.f};
            }
            const bf16* wp0 = Wt + ((size_t)e * KSTEPS * Mtot + col0) * 32 + quad * 8;
            const bf16* wp1 = Wt + ((size_t)e * KSTEPS * Mtot + col1) * 32 + quad * 8;
            #pragma unroll
            for (int ks = 0; ks < KSTEPS; ++ks) {
                const bf16x8 b0 = *(const bf16x8*)(wp0 + (size_t)ks * Mtot * 32);
                bf16x8 b1;
                if constexpr (TF == 2) b1 = *(const bf16x8*)(wp1 + (size_t)ks * Mtot * 32);
                #pragma unroll
                for (int rt = 0; rt < RF; ++rt) {
                    const bf16x8 av = *(const bf16x8*)(sA + (16 * rt + ml) * strideA + ks * 32 + quad * 8);
                    p0[rt] = __builtin_amdgcn_mfma_f32_16x16x32_bf16(av, b0, p0[rt], 0, 0, 0);
                    if constexpr (TF == 2)
                        p1[rt] = __builtin_amdgcn_mfma_f32_16x16x32_bf16(av, b1, p1[rt], 0, 0, 0);
                }
            }
            const float bv0 = (col0 < M) ? bias[(size_t)e * M + col0] : 0.f;
            float bv1 = 0.f;
            if constexpr (TF == 2) bv1 = (col1 < M) ? bias[(size_t)e * M + col1] : 0.f;
            #pragma unroll
            for (int rt = 0; rt < RF; ++rt)
                #pragma unroll
                for (int rg = 0; rg < 4; ++rg) {
                    const float s = sCo[e * ROWS + 16 * rt + quad * 4 + rg];
                    acc0[rt][rg] += s * (p0[rt][rg] + bv0);
                    if constexpr (TF == 2) acc1[rt][rg] += s * (p1[rt][rg] + bv1);
                }
        }
        #pragma unroll
        for (int rt = 0; rt < RF; ++rt)
            #pragma unroll
            for (int rg = 0; rg < 4; ++rg) {
                const int gr = row0 + 16 * rt + quad * 4 + rg;
                if (v0 && col0 < M) {
                    float v = acc0[rt][rg];
                    if (act) v = eluf(v);
                    if (Cf) Cf[(size_t)gr * ldc + col0] = v;
                    if (Cb) Cb[(size_t)gr * ldcb + col0] = __float2bfloat16(v);
                }
                if constexpr (TF == 2) {
                    if (v1 && col1 < M) {
                        float v = acc1[rt][rg];
                        if (act) v = eluf(v);
                        if (Cf) Cf[(size_t)gr * ldc + col1] = v;
                        if (Cb) Cb[(size_t)gr * ldcb + col1] = __float2bfloat16(v);
                    }
                }
            }
    }
}

// ---------------------------------------------------------------------------
// mid: mu|lv GEMM (M=64) + z + gate chain (g1,g2,logits) + softmax.
// One 32-row block per 32 batch rows; all deps are block-local. Grid: 128.
// ---------------------------------------------------------------------------
__global__ __launch_bounds__(256) void mid_kernel(
    const bf16* __restrict__ Axh2, const bf16* __restrict__ Wt_ml,
    const float* __restrict__ biasCat, const float* __restrict__ eps,
    float* __restrict__ out_mu, float* __restrict__ out_lv,
    bf16* __restrict__ Azc, bf16* __restrict__ Azd1, bf16* __restrict__ Azd2,
    const bf16* __restrict__ Wg0, const bf16* __restrict__ Wg1,
    const bf16* __restrict__ Wg2,
    const float* __restrict__ gb0, const float* __restrict__ gb1,
    const float* __restrict__ gb2, float* __restrict__ co)
{
    __shared__ bf16 sA[32 * 552];
    __shared__ char r1[11264];
    const int tid = threadIdx.x;
    const int w = tid >> 6, lane = tid & 63, ml = lane & 15, quad = lane >> 4;
    const int row0 = blockIdx.x * 32;

    float* sML = (float*)r1;                       // 32x64 f32 = 8KB
    {   // stage Axh2 rows (Kpad 544, stride 552)
        const int r = tid >> 3, kt = (tid & 7) * 8;
        for (int kk = kt; kk < 544; kk += 64)
            *(float4*)(sA + r * 552 + kk) =
                *(const float4*)(Axh2 + (size_t)(row0 + r) * 544 + kk);
    }
    __syncthreads();
    {   // mu|lv: M=64, wave w -> cols 16w..16w+15
        const int col = 16 * w + ml;
        f32x4 p0 = (f32x4){0.f, 0.f, 0.f, 0.f};
        f32x4 p1 = (f32x4){0.f, 0.f, 0.f, 0.f};
        const bf16* wp = Wt_ml + (size_t)col * 32 + quad * 8;
        #pragma unroll
        for (int ks = 0; ks < 17; ++ks) {
            const bf16x8 b  = *(const bf16x8*)(wp + (size_t)ks * 64 * 32);
            const bf16x8 a0 = *(const bf16x8*)(sA + ml * 552 + ks * 32 + quad * 8);
            const bf16x8 a1 = *(const bf16x8*)(sA + (16 + ml) * 552 + ks * 32 + quad * 8);
            p0 = __builtin_amdgcn_mfma_f32_16x16x32_bf16(a0, b, p0, 0, 0, 0);
            p1 = __builtin_amdgcn_mfma_f32_16x16x32_bf16(a1, b, p1, 0, 0, 0);
        }
        const float bv = biasCat[col];
        #pragma unroll
        for (int rg = 0; rg < 4; ++rg) {
            sML[(quad * 4 + rg) * 64 + col]      = p0[rg] + bv;
            sML[(16 + quad * 4 + rg) * 64 + col] = p1[rg] + bv;
        }
    }
    __syncthreads();
    for (int i = tid; i < 32 * LATENT; i += 256) {
        const int r = i >> 5, l = i & 31;
        const float m  = sML[r * 64 + l];
        const float lv = sML[r * 64 + 32 + l];
        const int gi = (row0 + r) * LATENT + l;
        out_mu[gi] = m; out_lv[gi] = lv;
        const bf16 zb = __float2bfloat16(m + eps[gi] * expf(0.5f * lv));
        Azc [(size_t)(row0 + r) * 320 + l] = zb;
        Azd1[(size_t)(row0 + r) * 288 + l] = zb;
        Azd2[(size_t)(row0 + r) * 288 + l] = zb;
    }
    __syncthreads();
    {   // re-stage gate A = Azc rows [z|c] (Kpad 320, stride 328)
        const int r = tid >> 3, kt = (tid & 7) * 8;
        for (int kk = kt; kk < 320; kk += 64)
            *(float4*)(sA + r * 328 + kk) =
                *(const float4*)(Azc + (size_t)(row0 + r) * 320 + kk);
    }
    bf16*  sG1 = (bf16*)r1;                        // 32x72 bf16
    bf16*  sG2 = (bf16*)(r1 + 4608);
    float* sLg = (float*)(r1 + 9216);              // 32x16 f32
    __syncthreads();
    {   // g1: K=320(10), M=64
        const int col = 16 * w + ml;
        f32x4 p0 = (f32x4){0.f, 0.f, 0.f, 0.f};
        f32x4 p1 = (f32x4){0.f, 0.f, 0.f, 0.f};
        const bf16* wp = Wg0 + (size_t)col * 32 + quad * 8;
        #pragma unroll
        for (int ks = 0; ks < 10; ++ks) {
            const bf16x8 b  = *(const bf16x8*)(wp + (size_t)ks * 64 * 32);
            const bf16x8 a0 = *(const bf16x8*)(sA + ml * 328 + ks * 32 + quad * 8);
            const bf16x8 a1 = *(const bf16x8*)(sA + (16 + ml) * 328 + ks * 32 + quad * 8);
            p0 = __builtin_amdgcn_mfma_f32_16x16x32_bf16(a0, b, p0, 0, 0, 0);
            p1 = __builtin_amdgcn_mfma_f32_16x16x32_bf16(a1, b, p1, 0, 0, 0);
        }
        const float bv = gb0[col];
        #pragma unroll
        for (int rg = 0; rg < 4; ++rg) {
            sG1[(quad * 4 + rg) * 72 + col]      = __float2bfloat16(eluf(p0[rg] + bv));
            sG1[(16 + quad * 4 + rg) * 72 + col] = __float2bfloat16(eluf(p1[rg] + bv));
        }
    }
    __syncthreads();
    {   // g2: K=64(2), M=64
        const int col = 16 * w + ml;
        f32x4 p0 = (f32x4){0.f, 0.f, 0.f, 0.f};
        f32x4 p1 = (f32x4){0.f, 0.f, 0.f, 0.f};
        const bf16* wp = Wg1 + (size_t)col * 32 + quad * 8;
        #pragma unroll
        for (int ks = 0; ks < 2; ++ks) {
            const bf16x8 b  = *(const bf16x8*)(wp + (size_t)ks * 64 * 32);
            const bf16x8 a0 = *(const bf16x8*)(sG1 + ml * 72 + ks * 32 + quad * 8);
            const bf16x8 a1 = *(const bf16x8*)(sG1 + (16 + ml) * 72 + ks * 32 + quad * 8);
            p0 = __builtin_amdgcn_mfma_f32_16x16x32_bf16(a0, b, p0, 0, 0, 0);
            p1 = __builtin_amdgcn_mfma_f32_16x16x32_bf16(a1, b, p1, 0, 0, 0);
        }
        const float bv = gb1[col];
        #pragma unroll
        for (int rg = 0; rg < 4; ++rg) {
            sG2[(quad * 4 + rg) * 72 + col]      = __float2bfloat16(eluf(p0[rg] + bv));
            sG2[(16 + quad * 4 + rg) * 72 + col] = __float2bfloat16(eluf(p1[rg] + bv));
        }
    }
    __syncthreads();
    if (w == 0) {   // logits: K=64(2), M=6 (Mtot 32)
        f32x4 p0 = (f32x4){0.f, 0.f, 0.f, 0.f};
        f32x4 p1 = (f32x4){0.f, 0.f, 0.f, 0.f};
        const bf16* wp = Wg2 + (size_t)ml * 32 + quad * 8;
        #pragma unroll
        for (int ks = 0; ks < 2; ++ks) {
            const bf16x8 b  = *(const bf16x8*)(wp + (size_t)ks * 32 * 32);
            const bf16x8 a0 = *(const bf16x8*)(sG2 + ml * 72 + ks * 32 + quad * 8);
            const bf16x8 a1 = *(const bf16x8*)(sG2 + (16 + ml) * 72 + ks * 32 + quad * 8);
            p0 = __builtin_amdgcn_mfma_f32_16x16x32_bf16(a0, b, p0, 0, 0, 0);
            p1 = __builtin_amdgcn_mfma_f32_16x16x32_bf16(a1, b, p1, 0, 0, 0);
        }
        const float bv = (ml < EXPERTS) ? gb2[ml] : 0.f;
        #pragma unroll
        for (int rg = 0; rg < 4; ++rg) {
            sLg[(quad * 4 + rg) * 16 + ml]      = p0[rg] + bv;
            sLg[(16 + quad * 4 + rg) * 16 + ml] = p1[rg] + bv;
        }
    }
    __syncthreads();
    if (tid < 32) {
        float v[EXPERTS];
        float m = -1e30f;
        #pragma unroll
        for (int i = 0; i < EXPERTS; ++i) { v[i] = sLg[tid * 16 + i]; m = fmaxf(m, v[i]); }
        float s = 0.f;
        #pragma unroll
        for (int i = 0; i < EXPERTS; ++i) { v[i] = expf(v[i] - m); s += v[i]; }
        const float inv = 1.f / s;
        #pragma unroll
        for (int i = 0; i < EXPERTS; ++i)
            co[(size_t)(row0 + tid) * EXPERTS + i] = v[i] * inv;
    }
}

// ---------------------------------------------------------------------------
extern "C" void kernel_launch(void* const* d_in, const int* in_sizes, int n_in,
                              void* d_out, int out_size, void* d_ws, size_t ws_size,
                              hipStream_t stream) {
    const float* x       = (const float*)d_in[0];
    const float* c       = (const float*)d_in[1];
    const float* eps     = (const float*)d_in[2];
    const float* enc_w1  = (const float*)d_in[3];
    const float* enc_b1  = (const float*)d_in[4];
    const float* enc_w2  = (const float*)d_in[5];
    const float* enc_b2  = (const float*)d_in[6];
    const float* enc_wmu = (const float*)d_in[7];
    const float* enc_bmu = (const float*)d_in[8];
    const float* enc_wlv = (const float*)d_in[9];
    const float* enc_blv = (const float*)d_in[10];
    const float* g_w0    = (const float*)d_in[11];
    const float* g_b0    = (const float*)d_in[12];
    const float* g_w1    = (const float*)d_in[13];
    const float* g_b1    = (const float*)d_in[14];
    const float* g_w2    = (const float*)d_in[15];
    const float* g_b2    = (const float*)d_in[16];
    const float* w0      = (const float*)d_in[17];
    const float* b0      = (const float*)d_in[18];
    const float* w1      = (const float*)d_in[19];
    const float* b1      = (const float*)d_in[20];
    const float* w2      = (const float*)d_in[21];
    const float* b2      = (const float*)d_in[22];

    // output (f32): [layer (4096x267) | mu (4096x32) | logvar (4096x32)]
    float* out_layer = (float*)d_out;
    float* out_mu    = out_layer + (size_t)N_BATCH * FRAME;
    float* out_lv    = out_mu    + (size_t)N_BATCH * LATENT;

    // ---- workspace layout (16B-aligned) ----
    char* p = (char*)d_ws;
    float* co      = (float*)p;  p += (size_t)N_BATCH * EXPERTS * 4;
    float* biasCat = (float*)p;  p += 64 * 4;
    bf16* Axc   = (bf16*)p;      p += (size_t)N_BATCH * 544 * 2;
    bf16* Axh1  = (bf16*)p;      p += (size_t)N_BATCH * 544 * 2;
    bf16* Axh2  = (bf16*)p;      p += (size_t)N_BATCH * 544 * 2;
    bf16* Azc   = (bf16*)p;      p += (size_t)N_BATCH * 320 * 2;
    bf16* Azd1  = (bf16*)p;      p += (size_t)N_BATCH * 288 * 2;
    bf16* Azd2  = (bf16*)p;      p += (size_t)N_BATCH * 288 * 2;
    bf16* Wt_e1 = (bf16*)p;      p += (size_t)17 * 256 * 32 * 2;
    bf16* Wt_e2 = (bf16*)p;      p += (size_t)17 * 256 * 32 * 2;
    bf16* Wt_ml = (bf16*)p;      p += (size_t)17 * 64 * 32 * 2;
    bf16* Wt_g0 = (bf16*)p;      p += (size_t)10 * 64 * 32 * 2;
    bf16* Wt_g1 = (bf16*)p;      p += (size_t)2 * 64 * 32 * 2;
    bf16* Wt_g2 = (bf16*)p;      p += (size_t)2 * 32 * 32 * 2;
    bf16* Wt_w0 = (bf16*)p;      p += (size_t)EXPERTS * 10 * 256 * 32 * 2;
    bf16* Wt_w1 = (bf16*)p;      p += (size_t)EXPERTS * 9 * 256 * 32 * 2;
    bf16* Wt_w2 = (bf16*)p;      p += (size_t)EXPERTS * 9 * 320 * 32 * 2;

    WTab tab;
    int cum = 0, n = 0;
    auto add = [&](const float* src, bf16* dst, int K, int M, int Mtot, int mOff, int E) {
        int Ksteps;
        if (K == 534 || K == 523) Ksteps = 17;
        else if (K == 299) Ksteps = 10;
        else if (K == 288) Ksteps = 9;
        else Ksteps = 2;   // K=64
        const int Mtiles = (M + 31) / 32;
        tab.e[n] = {src, dst, K, M, Mtot, mOff, Ksteps, Mtiles, cum};
        cum += E * Ksteps * Mtiles;
        ++n;
    };
    add(enc_w1,  Wt_e1, 534, 256, 256, 0, 1);
    add(enc_w2,  Wt_e2, 523, 256, 256, 0, 1);
    add(enc_wmu, Wt_ml, 523, 32, 64, 0, 1);
    add(enc_wlv, Wt_ml, 523, 32, 64, 32, 1);
    add(g_w0,    Wt_g0, 299, 64, 64, 0, 1);
    add(g_w1,    Wt_g1, 64, 64, 64, 0, 1);
    add(g_w2,    Wt_g2, 64, 6, 32, 0, 1);
    add(w0,      Wt_w0, 299, 256, 256, 0, EXPERTS);
    add(w1,      Wt_w1, 288, 256, 256, 0, EXPERTS);
    add(w2,      Wt_w2, 288, 267, 320, 0, EXPERTS);
    tab.total = cum;

    const dim3 blk(256);
    // LDS sizes: ROWS*(Kpad+8)*2 + ROWS*E*4
    const size_t smem_enc = (size_t)32 * 552 * 2 + 32 * 4;          // 35456
    const size_t smem_d0  = (size_t)64 * 328 * 2 + 64 * 6 * 4;      // 43520
    const size_t smem_d12 = (size_t)64 * 296 * 2 + 64 * 6 * 4;      // 39424

    // 0) prep: cvt (512 blocks) + weight repack (tab.total blocks)
    prep_kernel<<<dim3(512 + cum), blk, 0, stream>>>(x, c, enc_bmu, enc_blv,
        Axc, Axh1, Axh2, Azc, biasCat, tab);

    // 1) h1 = elu([x|c]@W+b) -> Axh1[:,267:523]   (RF=2, TF=2: 2 loads/4 mfma)
    gemm_k<17, 1, 2, 2><<<dim3(2, 128), blk, smem_enc, stream>>>(Axc, Wt_e1,
        enc_b1, nullptr, 256, 256, 8, nullptr, 0, Axh1 + FRAME, 544, 1);
    // 2) h2 = elu([x|h1]@W+b) -> Axh2[:,267:523]
    gemm_k<17, 1, 2, 2><<<dim3(2, 128), blk, smem_enc, stream>>>(Axh1, Wt_e2,
        enc_b2, nullptr, 256, 256, 8, nullptr, 0, Axh2 + FRAME, 544, 1);
    // 3) mu|lv + z + gate chain + softmax (fused, block-local deps)
    mid_kernel<<<dim3(128), blk, 0, stream>>>(Axh2, Wt_ml, biasCat, eps,
        out_mu, out_lv, Azc, Azd1, Azd2, Wt_g0, Wt_g1, Wt_g2,
        g_b0, g_b1, g_b2, co);
    // 4) dh1 = elu(moe([z|c], w0, b0)) -> Azd1[:,32:288]   (RF=4: 1 load/4 mfma)
    gemm_k<10, EXPERTS, 4, 1><<<dim3(4, 64), blk, smem_d0, stream>>>(Azc, Wt_w0,
        b0, co, 256, 256, 4, nullptr, 0, Azd1 + LATENT, 288, 1);
    // 5) dh2 = elu(moe([z|dh1], w1, b1)) -> Azd2[:,32:288]
    gemm_k<9, EXPERTS, 4, 1><<<dim3(4, 64), blk, smem_d12, stream>>>(Azd1, Wt_w1,
        b1, co, 256, 256, 4, nullptr, 0, Azd2 + LATENT, 288, 1);
    // 6) out = moe([z|dh2], w2, b2) -> d_out (f32)
    gemm_k<9, EXPERTS, 4, 1><<<dim3(4, 64), blk, smem_d12, stream>>>(Azd2, Wt_w2,
        b2, co, FRAME, 320, 5, out_layer, FRAME, nullptr, 0, 0);
}

// Round 10
// 199.700 us; speedup vs baseline: 3.6622x; 1.2441x over previous
//
#include <hip/hip_runtime.h>
#include <hip/hip_bf16.h>
#include <math.h>

// Problem constants (PoseMixtureVAE)
#define N_BATCH 4096
#define FRAME   267
#define LATENT  32
#define HIDDEN  256
#define GATE_H  64
#define EXPERTS 6
// Kpads: [x|c]=534->544 (17 ksteps), [x|h]=523->544 (17), [z|c]=299->320 (10),
//        [z|h]=288 (9), gate hidden 64 (2)

typedef __hip_bfloat16 bf16;
typedef __bf16  bf16x8 __attribute__((ext_vector_type(8)));
typedef float   f32x4  __attribute__((ext_vector_type(4)));

__device__ __forceinline__ float eluf(float v) { return (v > 0.f) ? v : (expf(v) - 1.f); }

struct WEnt { const float* src; bf16* dst; int K, M, Mtot, mOff, Ksteps, Mtiles, cum; };
struct WTab { WEnt e[10]; int total; };

// ---------------------------------------------------------------------------
// prep: input conversion (blocks 0..511, 8 rows each) + weight repack
// (blocks 512.., one 32x32 tile unit each) + biasCat.
// ---------------------------------------------------------------------------
__global__ __launch_bounds__(256) void prep_kernel(
    const float* __restrict__ x, const float* __restrict__ c,
    const float* __restrict__ bmu, const float* __restrict__ blv,
    bf16* __restrict__ Axc, bf16* __restrict__ Axh1,
    bf16* __restrict__ Axh2, bf16* __restrict__ Azc,
    float* __restrict__ biasCat, WTab tab)
{
    const int tid = threadIdx.x, bid = blockIdx.x;
    if (bid < 512) {
        if (bid == 0 && tid < 64)
            biasCat[tid] = (tid < 32) ? bmu[tid] : blv[tid - 32];
        #pragma unroll 1
        for (int i = 0; i < 8; ++i) {
            const int r = bid * 8 + i;
            for (int col = tid; col < 544; col += 256) {
                const size_t o = (size_t)r * 544 + col;
                float vx = 0.f;
                if (col < FRAME)          vx = x[(size_t)r * FRAME + col];
                else if (col < 2 * FRAME) vx = c[(size_t)r * FRAME + col - FRAME];
                Axc[o] = __float2bfloat16(vx);
                if (col < FRAME) {
                    const bf16 v = __float2bfloat16(x[(size_t)r * FRAME + col]);
                    Axh1[o] = v; Axh2[o] = v;
                } else if (col >= FRAME + HIDDEN) {
                    const bf16 zv = __float2bfloat16(0.f);
                    Axh1[o] = zv; Axh2[o] = zv;
                }
                if (col >= 32 && col < 320) {
                    const float vc = (col < 32 + FRAME) ? c[(size_t)r * FRAME + col - 32] : 0.f;
                    Azc[(size_t)r * 320 + col] = __float2bfloat16(vc);
                }
            }
        }
        return;
    }
    // weight repack unit
    __shared__ float tbuf[32][33];
    const int u = bid - 512;
    int i = 0;
    while (i < 9 && u >= tab.e[i + 1].cum) ++i;
    const WEnt en = tab.e[i];
    const int t = u - en.cum;
    const int perE = en.Ksteps * en.Mtiles;
    const int e = t / perE;
    const int rr = t - e * perE;
    const int mt = rr / en.Ksteps;
    const int ks = rr - mt * en.Ksteps;
    const int tx = tid & 31, ty = tid >> 5;
    const float* src = en.src + (size_t)e * en.K * en.M;
    #pragma unroll
    for (int i0 = 0; i0 < 32; i0 += 8) {
        const int k = ks * 32 + i0 + ty, m = mt * 32 + tx;
        tbuf[i0 + ty][tx] = (k < en.K && m < en.M) ? src[(size_t)k * en.M + m] : 0.f;
    }
    __syncthreads();
    bf16* dst = en.dst + ((size_t)(e * en.Ksteps + ks) * en.Mtot + en.mOff + mt * 32) * 32;
    #pragma unroll
    for (int i0 = 0; i0 < 32; i0 += 8)
        dst[(size_t)(i0 + ty) * 32 + tx] = __float2bfloat16(tbuf[tx][i0 + ty]);
}

// ---------------------------------------------------------------------------
// 16-row MFMA GEMM (TLP-first): C[n,m] = act( sum_e coeff[n,e]*(A@We + b_e) )
// Block = 16 rows x 64 cols, 4 waves, each wave exactly ONE 16-col tile.
// Grid (Mtot/64, 256) -> 1024+ blocks = 4+/CU = 16+ waves/CU (latency hiding).
// A (16 x Kpad) in LDS (one barrier); B streamed to regs, coalesced 1KB/wave
// from k-block repack [E][KSTEPS][Mtot][32]. LDS <= 17.7KB; VGPR capped 128.
// ---------------------------------------------------------------------------
template<int KSTEPS, int E>
__global__ __launch_bounds__(256, 4) void gemm16(
    const bf16* __restrict__ A, const bf16* __restrict__ Wt,
    const float* __restrict__ bias, const float* __restrict__ coeff,
    int M, int Mtot,
    float* __restrict__ Cf, int ldc, bf16* __restrict__ Cb, int ldcb, int act)
{
    constexpr int Kpad = KSTEPS * 32;
    constexpr int strideA = Kpad + 8;
    __shared__ bf16  sA[16 * strideA];
    __shared__ float sCo[E * 16];

    const int tid = threadIdx.x;
    const int w = tid >> 6, lane = tid & 63, ml = lane & 15, quad = lane >> 4;
    const int row0 = blockIdx.y * 16;
    const int col  = blockIdx.x * 64 + 16 * w + ml;

    if (tid < 16 * E) {
        const int e = tid >> 4, r = tid & 15;
        sCo[tid] = coeff ? coeff[(size_t)(row0 + r) * EXPERTS + e] : 1.f;
    }
    {   // stage A: 16 rows x Kpad, 16 threads/row x 16B chunks
        const int r = tid >> 4, kt = (tid & 15) * 8;
        for (int kk = kt; kk < Kpad; kk += 128)
            *(float4*)(sA + r * strideA + kk) =
                *(const float4*)(A + (size_t)(row0 + r) * Kpad + kk);
    }
    __syncthreads();

    f32x4 acc = (f32x4){0.f, 0.f, 0.f, 0.f};
    for (int e = 0; e < E; ++e) {
        f32x4 p = (f32x4){0.f, 0.f, 0.f, 0.f};
        const bf16* wp = Wt + ((size_t)e * KSTEPS * Mtot + col) * 32 + quad * 8;
        #pragma unroll
        for (int ks = 0; ks < KSTEPS; ++ks) {
            const bf16x8 b  = *(const bf16x8*)(wp + (size_t)ks * Mtot * 32);
            const bf16x8 av = *(const bf16x8*)(sA + ml * strideA + ks * 32 + quad * 8);
            p = __builtin_amdgcn_mfma_f32_16x16x32_bf16(av, b, p, 0, 0, 0);
        }
        const float bv = (col < M) ? bias[(size_t)e * M + col] : 0.f;
        #pragma unroll
        for (int rg = 0; rg < 4; ++rg)
            acc[rg] += sCo[e * 16 + quad * 4 + rg] * (p[rg] + bv);
    }

    if (col < M) {
        #pragma unroll
        for (int rg = 0; rg < 4; ++rg) {
            const int gr = row0 + quad * 4 + rg;
            float v = acc[rg];
            if (act) v = eluf(v);
            if (Cf) Cf[(size_t)gr * ldc + col] = v;
            if (Cb) Cb[(size_t)gr * ldcb + col] = __float2bfloat16(v);
        }
    }
}

// ---------------------------------------------------------------------------
// mid: mu|lv GEMM (M=64) + z + gate chain (g1,g2,logits) + softmax.
// 16-row blocks -> grid 256 (1/CU). All deps block-local.
// ---------------------------------------------------------------------------
__global__ __launch_bounds__(256) void mid_kernel(
    const bf16* __restrict__ Axh2, const bf16* __restrict__ Wt_ml,
    const float* __restrict__ biasCat, const float* __restrict__ eps,
    float* __restrict__ out_mu, float* __restrict__ out_lv,
    bf16* __restrict__ Azc, bf16* __restrict__ Azd1, bf16* __restrict__ Azd2,
    const bf16* __restrict__ Wg0, const bf16* __restrict__ Wg1,
    const bf16* __restrict__ Wg2,
    const float* __restrict__ gb0, const float* __restrict__ gb1,
    const float* __restrict__ gb2, float* __restrict__ co)
{
    __shared__ bf16 sA[16 * 552];
    __shared__ char r1[8192];
    const int tid = threadIdx.x;
    const int w = tid >> 6, lane = tid & 63, ml = lane & 15, quad = lane >> 4;
    const int row0 = blockIdx.x * 16;

    float* sML = (float*)r1;                       // 16x64 f32 = 4KB
    {   // stage Axh2 rows (Kpad 544, stride 552)
        const int r = tid >> 4, kt = (tid & 15) * 8;
        for (int kk = kt; kk < 544; kk += 128)
            *(float4*)(sA + r * 552 + kk) =
                *(const float4*)(Axh2 + (size_t)(row0 + r) * 544 + kk);
    }
    __syncthreads();
    {   // mu|lv: M=64, wave w -> cols 16w..16w+15 (16 rows, RF=1)
        const int col = 16 * w + ml;
        f32x4 p = (f32x4){0.f, 0.f, 0.f, 0.f};
        const bf16* wp = Wt_ml + (size_t)col * 32 + quad * 8;
        #pragma unroll
        for (int ks = 0; ks < 17; ++ks) {
            const bf16x8 b  = *(const bf16x8*)(wp + (size_t)ks * 64 * 32);
            const bf16x8 av = *(const bf16x8*)(sA + ml * 552 + ks * 32 + quad * 8);
            p = __builtin_amdgcn_mfma_f32_16x16x32_bf16(av, b, p, 0, 0, 0);
        }
        const float bv = biasCat[col];
        #pragma unroll
        for (int rg = 0; rg < 4; ++rg)
            sML[(quad * 4 + rg) * 64 + col] = p[rg] + bv;
    }
    __syncthreads();
    for (int i = tid; i < 16 * LATENT; i += 256) {
        const int r = i >> 5, l = i & 31;
        const float m  = sML[r * 64 + l];
        const float lv = sML[r * 64 + 32 + l];
        const int gi = (row0 + r) * LATENT + l;
        out_mu[gi] = m; out_lv[gi] = lv;
        const bf16 zb = __float2bfloat16(m + eps[gi] * expf(0.5f * lv));
        Azc [(size_t)(row0 + r) * 320 + l] = zb;
        Azd1[(size_t)(row0 + r) * 288 + l] = zb;
        Azd2[(size_t)(row0 + r) * 288 + l] = zb;
    }
    __syncthreads();
    {   // re-stage gate A = Azc rows [z|c] (Kpad 320, stride 328)
        const int r = tid >> 4, kt = (tid & 15) * 8;
        for (int kk = kt; kk < 320; kk += 128)
            *(float4*)(sA + r * 328 + kk) =
                *(const float4*)(Azc + (size_t)(row0 + r) * 320 + kk);
    }
    bf16*  sG1 = (bf16*)r1;                        // 16x72 bf16 = 2304B
    bf16*  sG2 = (bf16*)(r1 + 2304);
    float* sLg = (float*)(r1 + 4608);              // 16x16 f32 = 1024B
    __syncthreads();
    {   // g1: K=320(10), M=64
        const int col = 16 * w + ml;
        f32x4 p = (f32x4){0.f, 0.f, 0.f, 0.f};
        const bf16* wp = Wg0 + (size_t)col * 32 + quad * 8;
        #pragma unroll
        for (int ks = 0; ks < 10; ++ks) {
            const bf16x8 b  = *(const bf16x8*)(wp + (size_t)ks * 64 * 32);
            const bf16x8 av = *(const bf16x8*)(sA + ml * 328 + ks * 32 + quad * 8);
            p = __builtin_amdgcn_mfma_f32_16x16x32_bf16(av, b, p, 0, 0, 0);
        }
        const float bv = gb0[col];
        #pragma unroll
        for (int rg = 0; rg < 4; ++rg)
            sG1[(quad * 4 + rg) * 72 + col] = __float2bfloat16(eluf(p[rg] + bv));
    }
    __syncthreads();
    {   // g2: K=64(2), M=64
        const int col = 16 * w + ml;
        f32x4 p = (f32x4){0.f, 0.f, 0.f, 0.f};
        const bf16* wp = Wg1 + (size_t)col * 32 + quad * 8;
        #pragma unroll
        for (int ks = 0; ks < 2; ++ks) {
            const bf16x8 b  = *(const bf16x8*)(wp + (size_t)ks * 64 * 32);
            const bf16x8 av = *(const bf16x8*)(sG1 + ml * 72 + ks * 32 + quad * 8);
            p = __builtin_amdgcn_mfma_f32_16x16x32_bf16(av, b, p, 0, 0, 0);
        }
        const float bv = gb1[col];
        #pragma unroll
        for (int rg = 0; rg < 4; ++rg)
            sG2[(quad * 4 + rg) * 72 + col] = __float2bfloat16(eluf(p[rg] + bv));
    }
    __syncthreads();
    if (w == 0) {   // logits: K=64(2), M=6 (Mtot 32)
        f32x4 p = (f32x4){0.f, 0.f, 0.f, 0.f};
        const bf16* wp = Wg2 + (size_t)ml * 32 + quad * 8;
        #pragma unroll
        for (int ks = 0; ks < 2; ++ks) {
            const bf16x8 b  = *(const bf16x8*)(wp + (size_t)ks * 32 * 32);
            const bf16x8 av = *(const bf16x8*)(sG2 + ml * 72 + ks * 32 + quad * 8);
            p = __builtin_amdgcn_mfma_f32_16x16x32_bf16(av, b, p, 0, 0, 0);
        }
        const float bv = (ml < EXPERTS) ? gb2[ml] : 0.f;
        #pragma unroll
        for (int rg = 0; rg < 4; ++rg)
            sLg[(quad * 4 + rg) * 16 + ml] = p[rg] + bv;
    }
    __syncthreads();
    if (tid < 16) {
        float v[EXPERTS];
        float m = -1e30f;
        #pragma unroll
        for (int i = 0; i < EXPERTS; ++i) { v[i] = sLg[tid * 16 + i]; m = fmaxf(m, v[i]); }
        float s = 0.f;
        #pragma unroll
        for (int i = 0; i < EXPERTS; ++i) { v[i] = expf(v[i] - m); s += v[i]; }
        const float inv = 1.f / s;
        #pragma unroll
        for (int i = 0; i < EXPERTS; ++i)
            co[(size_t)(row0 + tid) * EXPERTS + i] = v[i] * inv;
    }
}

// ---------------------------------------------------------------------------
extern "C" void kernel_launch(void* const* d_in, const int* in_sizes, int n_in,
                              void* d_out, int out_size, void* d_ws, size_t ws_size,
                              hipStream_t stream) {
    const float* x       = (const float*)d_in[0];
    const float* c       = (const float*)d_in[1];
    const float* eps     = (const float*)d_in[2];
    const float* enc_w1  = (const float*)d_in[3];
    const float* enc_b1  = (const float*)d_in[4];
    const float* enc_w2  = (const float*)d_in[5];
    const float* enc_b2  = (const float*)d_in[6];
    const float* enc_wmu = (const float*)d_in[7];
    const float* enc_bmu = (const float*)d_in[8];
    const float* enc_wlv = (const float*)d_in[9];
    const float* enc_blv = (const float*)d_in[10];
    const float* g_w0    = (const float*)d_in[11];
    const float* g_b0    = (const float*)d_in[12];
    const float* g_w1    = (const float*)d_in[13];
    const float* g_b1    = (const float*)d_in[14];
    const float* g_w2    = (const float*)d_in[15];
    const float* g_b2    = (const float*)d_in[16];
    const float* w0      = (const float*)d_in[17];
    const float* b0      = (const float*)d_in[18];
    const float* w1      = (const float*)d_in[19];
    const float* b1      = (const float*)d_in[20];
    const float* w2      = (const float*)d_in[21];
    const float* b2      = (const float*)d_in[22];

    // output (f32): [layer (4096x267) | mu (4096x32) | logvar (4096x32)]
    float* out_layer = (float*)d_out;
    float* out_mu    = out_layer + (size_t)N_BATCH * FRAME;
    float* out_lv    = out_mu    + (size_t)N_BATCH * LATENT;

    // ---- workspace layout (16B-aligned) ----
    char* p = (char*)d_ws;
    float* co      = (float*)p;  p += (size_t)N_BATCH * EXPERTS * 4;
    float* biasCat = (float*)p;  p += 64 * 4;
    bf16* Axc   = (bf16*)p;      p += (size_t)N_BATCH * 544 * 2;
    bf16* Axh1  = (bf16*)p;      p += (size_t)N_BATCH * 544 * 2;
    bf16* Axh2  = (bf16*)p;      p += (size_t)N_BATCH * 544 * 2;
    bf16* Azc   = (bf16*)p;      p += (size_t)N_BATCH * 320 * 2;
    bf16* Azd1  = (bf16*)p;      p += (size_t)N_BATCH * 288 * 2;
    bf16* Azd2  = (bf16*)p;      p += (size_t)N_BATCH * 288 * 2;
    bf16* Wt_e1 = (bf16*)p;      p += (size_t)17 * 256 * 32 * 2;
    bf16* Wt_e2 = (bf16*)p;      p += (size_t)17 * 256 * 32 * 2;
    bf16* Wt_ml = (bf16*)p;      p += (size_t)17 * 64 * 32 * 2;
    bf16* Wt_g0 = (bf16*)p;      p += (size_t)10 * 64 * 32 * 2;
    bf16* Wt_g1 = (bf16*)p;      p += (size_t)2 * 64 * 32 * 2;
    bf16* Wt_g2 = (bf16*)p;      p += (size_t)2 * 32 * 32 * 2;
    bf16* Wt_w0 = (bf16*)p;      p += (size_t)EXPERTS * 10 * 256 * 32 * 2;
    bf16* Wt_w1 = (bf16*)p;      p += (size_t)EXPERTS * 9 * 256 * 32 * 2;
    bf16* Wt_w2 = (bf16*)p;      p += (size_t)EXPERTS * 9 * 320 * 32 * 2;

    WTab tab;
    int cum = 0, n = 0;
    auto add = [&](const float* src, bf16* dst, int K, int M, int Mtot, int mOff, int E) {
        int Ksteps;
        if (K == 534 || K == 523) Ksteps = 17;
        else if (K == 299) Ksteps = 10;
        else if (K == 288) Ksteps = 9;
        else Ksteps = 2;   // K=64
        const int Mtiles = (M + 31) / 32;
        tab.e[n] = {src, dst, K, M, Mtot, mOff, Ksteps, Mtiles, cum};
        cum += E * Ksteps * Mtiles;
        ++n;
    };
    add(enc_w1,  Wt_e1, 534, 256, 256, 0, 1);
    add(enc_w2,  Wt_e2, 523, 256, 256, 0, 1);
    add(enc_wmu, Wt_ml, 523, 32, 64, 0, 1);
    add(enc_wlv, Wt_ml, 523, 32, 64, 32, 1);
    add(g_w0,    Wt_g0, 299, 64, 64, 0, 1);
    add(g_w1,    Wt_g1, 64, 64, 64, 0, 1);
    add(g_w2,    Wt_g2, 64, 6, 32, 0, 1);
    add(w0,      Wt_w0, 299, 256, 256, 0, EXPERTS);
    add(w1,      Wt_w1, 288, 256, 256, 0, EXPERTS);
    add(w2,      Wt_w2, 288, 267, 320, 0, EXPERTS);
    tab.total = cum;

    const dim3 blk(256);
    const int gy = N_BATCH / 16;   // 256 row-blocks

    // 0) prep: cvt (512 blocks) + weight repack
    prep_kernel<<<dim3(512 + cum), blk, 0, stream>>>(x, c, enc_bmu, enc_blv,
        Axc, Axh1, Axh2, Azc, biasCat, tab);

    // 1) h1 = elu([x|c]@W+b) -> Axh1[:,267:523]   grid (4,256)=1024 blocks
    gemm16<17, 1><<<dim3(4, gy), blk, 0, stream>>>(Axc, Wt_e1, enc_b1,
        nullptr, 256, 256, nullptr, 0, Axh1 + FRAME, 544, 1);
    // 2) h2 = elu([x|h1]@W+b) -> Axh2[:,267:523]
    gemm16<17, 1><<<dim3(4, gy), blk, 0, stream>>>(Axh1, Wt_e2, enc_b2,
        nullptr, 256, 256, nullptr, 0, Axh2 + FRAME, 544, 1);
    // 3) mu|lv + z + gate chain + softmax (fused; 256 blocks)
    mid_kernel<<<dim3(gy), blk, 0, stream>>>(Axh2, Wt_ml, biasCat, eps,
        out_mu, out_lv, Azc, Azd1, Azd2, Wt_g0, Wt_g1, Wt_g2,
        g_b0, g_b1, g_b2, co);
    // 4) dh1 = elu(moe([z|c], w0, b0)) -> Azd1[:,32:288]
    gemm16<10, EXPERTS><<<dim3(4, gy), blk, 0, stream>>>(Azc, Wt_w0, b0,
        co, 256, 256, nullptr, 0, Azd1 + LATENT, 288, 1);
    // 5) dh2 = elu(moe([z|dh1], w1, b1)) -> Azd2[:,32:288]
    gemm16<9, EXPERTS><<<dim3(4, gy), blk, 0, stream>>>(Azd1, Wt_w1, b1,
        co, 256, 256, nullptr, 0, Azd2 + LATENT, 288, 1);
    // 6) out = moe([z|dh2], w2, b2) -> d_out (f32)   grid (5,256)=1280 blocks
    gemm16<9, EXPERTS><<<dim3(5, gy), blk, 0, stream>>>(Azd2, Wt_w2, b2,
        co, FRAME, 320, out_layer, FRAME, nullptr, 0, 0);
}